// Round 7
// baseline (343.816 us; speedup 1.0000x reference)
//
#include <hip/hip_runtime.h>
#include <stdint.h>
#include <math.h>

typedef __bf16 bf16x8 __attribute__((ext_vector_type(8)));
typedef float f32x4 __attribute__((ext_vector_type(4)));
typedef unsigned short us8 __attribute__((ext_vector_type(8)));
typedef unsigned short us4 __attribute__((ext_vector_type(4)));

#define DD 128      // feature dim
#define TILE 64     // edges per block-tile

__device__ __forceinline__ unsigned short f2bf(float f) {
    __bf16 b = (__bf16)f;                  // native v_cvt (RNE)
    return __builtin_bit_cast(unsigned short, b);
}

__device__ __forceinline__ float fsilu(float x) {
    float e = __expf(-x);
    return x * __builtin_amdgcn_rcpf(1.0f + e);
}

__device__ __forceinline__ float dec1(unsigned int u) {
    float z = (float)(u & 0x1FFFFu) * (1.0f / 2048.0f) - 36.0f;
    float s = __builtin_amdgcn_rcpf(1.0f + __expf(-z));
    return __logf(s + 1e-10f);
}

__global__ void decode_log(unsigned int* __restrict__ p, long n) {
    long i = (long)blockIdx.x * blockDim.x + threadIdx.x;
    long stride = (long)gridDim.x * blockDim.x;
    long n4 = n >> 2;
    for (long k = i; k < n4; k += stride) {
        uint4 u = ((uint4*)p)[k];
        float4 r;
        r.x = dec1(u.x); r.y = dec1(u.y); r.z = dec1(u.z); r.w = dec1(u.w);
        ((float4*)p)[k] = r;
    }
    for (long k = (n4 << 2) + i; k < n; k += stride) {
        unsigned int u = p[k];
        ((float*)p)[k] = dec1(u);
    }
}

// Block: 256 threads = 4 waves. Tile: 64 edges x 128 features, K=128.
// R6 structure (2 barriers/tile, swapped-operand MFMA, XOR-swizzled LDS,
// z-in-VALU) with ONE change: __launch_bounds__(256, 3) forces the
// allocator to fit 3 waves/SIMD (<=~170 arch+acc regs) -> 3 blocks/CU
// instead of 2, so different blocks' complementary phases (stage=VALU/DS,
// L1/L2=DS+MFMA, z=VALU) overlap across waves.
__global__ __launch_bounds__(256, 3)
void mlp_scatter(const float* __restrict__ A,
                 const int* __restrict__ eidx,
                 const float* __restrict__ W1, const float* __restrict__ B1,
                 const float* __restrict__ W2, const float* __restrict__ B2,
                 const float* __restrict__ WO, const float* __restrict__ BO,
                 unsigned int* __restrict__ out,
                 int E, int numTiles, int tpb, int N)
{
    __shared__ unsigned short Abuf[TILE * DD];   // 16 KB: edge_attr bf16 (swizzled)
    __shared__ unsigned short Hbuf[TILE * DD];   // 16 KB: H1 bf16 (swizzled)
    __shared__ float zbuf[TILE * 4];             // 1 KB: per-wave z partials [e][wave]

    const int tid  = threadIdx.x;
    const int lane = tid & 63;
    const int wave = tid >> 6;
    const int lrow = lane & 15;          // frag row/col index
    const int lg   = lane >> 4;          // 4 lane-groups
    const int lkb  = lg * 16;            // byte offset of this lane's 8-bf16 k-slice

    // ---- W1/W2 A-fragments: lane holds W[f = 32w+16mt+lrow][k-slice] ----
    bf16x8 w1f[2][4], w2f[2][4];
    float4 bias1[2], bias2[2], wo4[2];
    #pragma unroll
    for (int mt = 0; mt < 2; ++mt) {
        int f = wave * 32 + mt * 16 + lrow;
        bias1[mt] = *(const float4*)(B1 + wave * 32 + mt * 16 + lg * 4);
        bias2[mt] = *(const float4*)(B2 + wave * 32 + mt * 16 + lg * 4);
        wo4[mt]   = *(const float4*)(WO + wave * 32 + mt * 16 + lg * 4);
        #pragma unroll
        for (int kk = 0; kk < 4; ++kk) {
            const float* p1 = W1 + f * DD + kk * 32 + lg * 8;
            const float* p2 = W2 + f * DD + kk * 32 + lg * 8;
            us8 t1, t2;
            #pragma unroll
            for (int j = 0; j < 8; ++j) { t1[j] = f2bf(p1[j]); t2[j] = f2bf(p2[j]); }
            w1f[mt][kk] = __builtin_bit_cast(bf16x8, t1);
            w2f[mt][kk] = __builtin_bit_cast(bf16x8, t2);
        }
    }
    const float bo = BO[0];
    const size_t NN = (size_t)N * (size_t)N;
    const int gs = (int)gridDim.x;

    int t0 = blockIdx.x;
    if (t0 >= numTiles) return;

    // ---- prologue: load + stage tile t0, prefetch t0+gs ----
    float4 v[8];
    {
        const float4* src = (const float4*)(A + (long)t0 * TILE * DD);
        #pragma unroll
        for (int s = 0; s < 8; ++s) v[s] = src[s * 256 + tid];
    }
    #pragma unroll
    for (int s = 0; s < 8; ++s) {
        int id  = s * 256 + tid;           // 2048 float4 = 64 rows x 32
        int row = id >> 5;
        int cb  = (id & 31) * 8;           // byte offset (4 ushorts)
        us4 o;
        o[0] = f2bf(v[s].x); o[1] = f2bf(v[s].y); o[2] = f2bf(v[s].z); o[3] = f2bf(v[s].w);
        *(us4*)((char*)Abuf + row * 256 + (cb ^ ((row & 7) << 4))) = o;
    }
    {
        int tn = t0 + gs; if (tn >= numTiles) tn = t0;
        const float4* src = (const float4*)(A + (long)tn * TILE * DD);
        #pragma unroll
        for (int s = 0; s < 8; ++s) v[s] = src[s * 256 + tid];
    }
    __syncthreads();

    for (int t = t0; t < numTiles; t += gs) {
        // ---- hoist eidx loads for this tile's scatter ----
        int i0 = 0, j0 = 0, sb = 0, sei = 0;
        if (lane < 16) {
            int e = wave * 16 + lane;
            sb  = t / tpb;
            sei = (t - sb * tpb) * TILE + e;
            i0 = eidx[(size_t)(2 * sb) * E + sei];
            j0 = eidx[(size_t)(2 * sb + 1) * E + sei];
        }

        // ---- layer 1 (swapped): C1[f][e] from Abuf ----
        f32x4 acc1[2][4];
        #pragma unroll
        for (int mt = 0; mt < 2; ++mt)
            #pragma unroll
            for (int nt = 0; nt < 4; ++nt)
                acc1[mt][nt] = (f32x4){0.f, 0.f, 0.f, 0.f};
        #pragma unroll
        for (int kk = 0; kk < 4; ++kk) {
            bf16x8 ef[4];
            #pragma unroll
            for (int nt = 0; nt < 4; ++nt) {
                int e = nt * 16 + lrow;
                ef[nt] = *(const bf16x8*)((const char*)Abuf + e * 256 +
                                          ((kk * 64 + lkb) ^ ((e & 7) << 4)));
            }
            #pragma unroll
            for (int mt = 0; mt < 2; ++mt)
                #pragma unroll
                for (int nt = 0; nt < 4; ++nt)
                    acc1[mt][nt] = __builtin_amdgcn_mfma_f32_16x16x32_bf16(w1f[mt][kk], ef[nt], acc1[mt][nt], 0, 0, 0);
        }
        // epilogue: silu+bias -> packed b64 writes into Hbuf[e][f] (swizzled)
        #pragma unroll
        for (int mt = 0; mt < 2; ++mt)
            #pragma unroll
            for (int nt = 0; nt < 4; ++nt) {
                int e  = nt * 16 + lrow;
                int fb = (wave * 32 + mt * 16 + lg * 4) * 2;   // byte col of f0
                us4 o;
                #pragma unroll
                for (int i = 0; i < 4; ++i) {
                    float h = fsilu(acc1[mt][nt][i] + bias1[mt][i]);
                    o[i] = f2bf(h);
                }
                *(us4*)((char*)Hbuf + e * 256 + (fb ^ ((e & 7) << 4))) = o;
            }
        __syncthreads();   // S1: Hbuf ready; all Abuf reads of tile t done

        // ---- stage tile t+gs from v into Abuf (overlaps L2 below) ----
        #pragma unroll
        for (int s = 0; s < 8; ++s) {
            int id  = s * 256 + tid;
            int row = id >> 5;
            int cb  = (id & 31) * 8;
            us4 o;
            o[0] = f2bf(v[s].x); o[1] = f2bf(v[s].y); o[2] = f2bf(v[s].z); o[3] = f2bf(v[s].w);
            *(us4*)((char*)Abuf + row * 256 + (cb ^ ((row & 7) << 4))) = o;
        }
        // ---- prefetch tile t+2*gs into v ----
        {
            int tn = t + 2 * gs; if (tn >= numTiles) tn = t;
            const float4* src = (const float4*)(A + (long)tn * TILE * DD);
            #pragma unroll
            for (int s = 0; s < 8; ++s) v[s] = src[s * 256 + tid];
        }

        // ---- layer 2 (swapped): C2[f][e] from Hbuf; H2 stays in regs ----
        f32x4 acc2[2][4];
        #pragma unroll
        for (int mt = 0; mt < 2; ++mt)
            #pragma unroll
            for (int nt = 0; nt < 4; ++nt)
                acc2[mt][nt] = (f32x4){0.f, 0.f, 0.f, 0.f};
        #pragma unroll
        for (int kk = 0; kk < 4; ++kk) {
            bf16x8 ef[4];
            #pragma unroll
            for (int nt = 0; nt < 4; ++nt) {
                int e = nt * 16 + lrow;
                ef[nt] = *(const bf16x8*)((const char*)Hbuf + e * 256 +
                                          ((kk * 64 + lkb) ^ ((e & 7) << 4)));
            }
            #pragma unroll
            for (int mt = 0; mt < 2; ++mt)
                #pragma unroll
                for (int nt = 0; nt < 4; ++nt)
                    acc2[mt][nt] = __builtin_amdgcn_mfma_f32_16x16x32_bf16(w2f[mt][kk], ef[nt], acc2[mt][nt], 0, 0, 0);
        }

        // ---- z partials in VALU: zp[nt] = sum over this wave's f-slice ----
        float zp[4] = {0.f, 0.f, 0.f, 0.f};
        #pragma unroll
        for (int mt = 0; mt < 2; ++mt)
            #pragma unroll
            for (int nt = 0; nt < 4; ++nt)
                #pragma unroll
                for (int i = 0; i < 4; ++i) {
                    float h = fsilu(acc2[mt][nt][i] + bias2[mt][i]);
                    zp[nt] += wo4[mt][i] * h;
                }
        #pragma unroll
        for (int nt = 0; nt < 4; ++nt) {        // reduce over lane-groups
            zp[nt] += __shfl_xor(zp[nt], 16);
            zp[nt] += __shfl_xor(zp[nt], 32);
        }
        if (lg == 0) {
            #pragma unroll
            for (int nt = 0; nt < 4; ++nt)
                zbuf[(nt * 16 + lrow) * 4 + wave] = zp[nt];
        }
        __syncthreads();   // S2: zbuf ready; Hbuf reads done; Abuf staged

        // ---- final z, pack, atomicMax scatter (16 lanes/wave, 64 edges) ----
        if (lane < 16) {
            int e = wave * 16 + lane;
            float4 zb = *(const float4*)&zbuf[e * 4];
            float z = ((zb.x + zb.y) + (zb.z + zb.w)) + bo;
            int qz = (int)((z + 36.0f) * 2048.0f + 0.5f);
            qz = qz < 0 ? 0 : (qz > 131071 ? 131071 : qz);
            unsigned int packed = (((unsigned int)(sei + 1)) << 17) | (unsigned int)qz;
            atomicMax(&out[(size_t)sb * NN + (size_t)i0 * N + (size_t)j0], packed);
        }
    }
}

extern "C" void kernel_launch(void* const* d_in, const int* in_sizes, int n_in,
                              void* d_out, int out_size, void* d_ws, size_t ws_size,
                              hipStream_t stream) {
    const float* edge_attr  = (const float*)d_in[0];
    const int*   edge_index = (const int*)d_in[1];
    const float* W1   = (const float*)d_in[2];
    const float* b1   = (const float*)d_in[3];
    const float* W2   = (const float*)d_in[4];
    const float* b2   = (const float*)d_in[5];
    const float* Wout = (const float*)d_in[6];
    const float* bout = (const float*)d_in[7];

    long rows = (long)in_sizes[0] / DD;        // B*E = 1,024,000
    int  E    = in_sizes[1] / 64;              // 32000 (B=32)
    int  numTiles = (int)(rows / TILE);        // 16000
    int  tpb  = E / TILE;                      // tiles per batch = 500
    int  Bb   = (int)(rows / E);               // 32
    int  N    = (int)(sqrtf((float)(out_size / Bb)) + 0.5f);   // 1000

    unsigned int* outp = (unsigned int*)d_out;
    long n = (long)out_size;

    hipMemsetAsync(d_out, 0, (size_t)out_size * sizeof(unsigned int), stream);
    mlp_scatter<<<2048, 256, 0, stream>>>(edge_attr, edge_index, W1, b1, W2, b2,
                                          Wout, bout, outp, E, numTiles, tpb, N);
    decode_log<<<2048, 256, 0, stream>>>(outp, n);
}

// Round 8
// 217.460 us; speedup vs baseline: 1.5811x; 1.5811x over previous
//
#include <hip/hip_runtime.h>
#include <stdint.h>
#include <string.h>
#include <math.h>

typedef __bf16 bf16x8 __attribute__((ext_vector_type(8)));
typedef float f32x4 __attribute__((ext_vector_type(4)));
typedef unsigned short us8 __attribute__((ext_vector_type(8)));
typedef unsigned int u32;

#define DD 128

__device__ __forceinline__ unsigned short f2bf(float f) {
    __bf16 b = (__bf16)f;                  // native v_cvt (RNE)
    return __builtin_bit_cast(unsigned short, b);
}
__device__ __forceinline__ u32 pack2(float a, float b) {
    return (u32)f2bf(a) | ((u32)f2bf(b) << 16);
}
__device__ __forceinline__ float fsilu(float x) {
    float e = __expf(-x);
    return x * __builtin_amdgcn_rcpf(1.0f + e);
}

// ---- fill: write the final "unset" float (log(1e-10)) everywhere ----
__global__ void fill_const(u32* __restrict__ p, long n4, u32 val) {
    long i  = (long)blockIdx.x * blockDim.x + threadIdx.x;
    long st = (long)gridDim.x * blockDim.x;
    uint4 v4 = make_uint4(val, val, val, val);
    for (long k = i; k < n4; k += st) ((uint4*)p)[k] = v4;
}

// ---- sparse decode: only scatter-touched cells (>= 0xE0000000) ----
__device__ __forceinline__ float decz(u32 u) {
    float z = (float)(int)(u & 0x3FFFu) * (1.0f / 256.0f) - 40.0f;
    float s = __builtin_amdgcn_rcpf(1.0f + __expf(-z));
    return __logf(s + 1e-10f);
}
__global__ void decode_sparse(u32* __restrict__ p, long n4) {
    long i  = (long)blockIdx.x * blockDim.x + threadIdx.x;
    long st = (long)gridDim.x * blockDim.x;
    for (long k = i; k < n4; k += st) {
        uint4 u = ((const uint4*)p)[k];
        float* f = (float*)(p + k * 4);
        if (u.x >= 0xE0000000u) f[0] = decz(u.x);
        if (u.y >= 0xE0000000u) f[1] = decz(u.y);
        if (u.z >= 0xE0000000u) f[2] = decz(u.z);
        if (u.w >= 0xE0000000u) f[3] = decz(u.w);
    }
}

// Wave-independent MLP+scatter. Block = 1024 threads = 16 waves.
// LDS (dynamic, 132608 B): W1s/W2s bf16 [f][k] swizzled (byte ^= (f&7)<<4),
// b1/b2/wo f32, Hs = per-wave 4 KB H1 scratch. One barrier after W staging,
// then every wave owns 16 edges end-to-end with NO barriers:
//   load 16e x 128k fp32 (coalesced 128B rows) -> bf16 B-frags
//   L1: acc[f][e] = mfma(W1frag, edgefrag), acc init = b1
//   silu -> pack -> Hs (b64, swizzled)       [same-wave, lgkmcnt only]
//   L2: acc2 = mfma(W2frag, Hsfrag), init = b2
//   z = wo . silu(acc2) reduced via shfl_xor(16,32)
//   scatter: atomicMax(out, 0xE0000000 | (ei+1)<<14 | qz14)
// Fragment mappings identical to the R4-validated kernel.
__global__ __launch_bounds__(1024)
void mlp_scatter(const float* __restrict__ A,
                 const int* __restrict__ eidx,
                 const float* __restrict__ W1, const float* __restrict__ B1,
                 const float* __restrict__ W2, const float* __restrict__ B2,
                 const float* __restrict__ WO, const float* __restrict__ BO,
                 u32* __restrict__ out,
                 int E, int nWT, int N)
{
    extern __shared__ char smem[];
    unsigned short* W1s = (unsigned short*)smem;             // 32 KB
    unsigned short* W2s = (unsigned short*)(smem + 32768);   // 32 KB
    float* b1s = (float*)(smem + 65536);                     // 512 B
    float* b2s = (float*)(smem + 66048);                     // 512 B
    float* wos = (float*)(smem + 66560);                     // 512 B
    char*  Hs  = smem + 67072;                               // 64 KB (16 x 4 KB)

    const int tid  = threadIdx.x;
    const int lane = tid & 63;
    const int wave = tid >> 6;
    const int lrow = lane & 15;
    const int lg   = lane >> 4;

    // ---- stage W1/W2 fp32 -> bf16 LDS, swizzled [f][k] (coalesced) ----
    #pragma unroll
    for (int c = 0; c < 2; ++c) {
        int id = c * 1024 + tid;           // 2048 ids x 8 elems = 16384
        int f  = id >> 4;
        int kb = (id & 15) * 8;
        const float* s1 = W1 + f * DD + kb;
        const float* s2 = W2 + f * DD + kb;
        float4 a0 = *(const float4*)s1, a1 = *(const float4*)(s1 + 4);
        float4 c0 = *(const float4*)s2, c1 = *(const float4*)(s2 + 4);
        us8 t1, t2;
        t1[0]=f2bf(a0.x); t1[1]=f2bf(a0.y); t1[2]=f2bf(a0.z); t1[3]=f2bf(a0.w);
        t1[4]=f2bf(a1.x); t1[5]=f2bf(a1.y); t1[6]=f2bf(a1.z); t1[7]=f2bf(a1.w);
        t2[0]=f2bf(c0.x); t2[1]=f2bf(c0.y); t2[2]=f2bf(c0.z); t2[3]=f2bf(c0.w);
        t2[4]=f2bf(c1.x); t2[5]=f2bf(c1.y); t2[6]=f2bf(c1.z); t2[7]=f2bf(c1.w);
        int off = f * 256 + ((kb * 2) ^ ((f & 7) << 4));
        *(us8*)((char*)W1s + off) = t1;
        *(us8*)((char*)W2s + off) = t2;
    }
    if (tid < DD) { b1s[tid] = B1[tid]; b2s[tid] = B2[tid]; wos[tid] = WO[tid]; }
    const float bo = BO[0];
    const size_t NN = (size_t)N * (size_t)N;
    char* HsW = Hs + wave * 4096;
    __syncthreads();   // the ONLY barrier

    const int wid  = blockIdx.x * 16 + wave;
    const int step = (int)gridDim.x * 16;

    for (int wt = wid; wt < nWT; wt += step) {
        const int r0  = wt << 4;              // global edge-row base
        const int b   = r0 / E;               // wave-uniform (E % 16 == 0)
        const int ei0 = r0 - b * E;
        int i0 = 0, j0 = 0;
        if (lane < 16) {
            i0 = eidx[(size_t)(2 * b) * E + ei0 + lane];
            j0 = eidx[(size_t)(2 * b + 1) * E + ei0 + lane];
        }

        // ---- load this wave's 16 edges (16 rows x 128 B contiguous / kk) ----
        const float* Ar = A + (size_t)(r0 + lrow) * DD;
        float4 e0[4], e1[4];
        #pragma unroll
        for (int kk = 0; kk < 4; ++kk) {
            const float* p = Ar + kk * 32 + lg * 8;
            e0[kk] = *(const float4*)p;
            e1[kk] = *(const float4*)(p + 4);
        }

        // ---- layer 1: C1[f][e], acc init = b1 ----
        f32x4 acc[8];
        #pragma unroll
        for (int mt = 0; mt < 8; ++mt)
            acc[mt] = *(const f32x4*)&b1s[mt * 16 + lg * 4];
        #pragma unroll
        for (int kk = 0; kk < 4; ++kk) {
            us8 t;
            t[0]=f2bf(e0[kk].x); t[1]=f2bf(e0[kk].y); t[2]=f2bf(e0[kk].z); t[3]=f2bf(e0[kk].w);
            t[4]=f2bf(e1[kk].x); t[5]=f2bf(e1[kk].y); t[6]=f2bf(e1[kk].z); t[7]=f2bf(e1[kk].w);
            bf16x8 ef = __builtin_bit_cast(bf16x8, t);
            #pragma unroll
            for (int mt = 0; mt < 8; ++mt) {
                int f = mt * 16 + lrow;
                bf16x8 wf = *(const bf16x8*)((const char*)W1s + f * 256 +
                                             ((kk * 64 + lg * 16) ^ ((f & 7) << 4)));
                acc[mt] = __builtin_amdgcn_mfma_f32_16x16x32_bf16(wf, ef, acc[mt], 0, 0, 0);
            }
        }

        // ---- silu -> bf16 pack -> per-wave Hs (b64, swizzled) ----
        #pragma unroll
        for (int mt = 0; mt < 8; ++mt) {
            u32 p0 = pack2(fsilu(acc[mt][0]), fsilu(acc[mt][1]));
            u32 p1 = pack2(fsilu(acc[mt][2]), fsilu(acc[mt][3]));
            *(uint2*)(HsW + lrow * 256 + ((mt * 32 + lg * 8) ^ ((lrow & 7) << 4))) =
                make_uint2(p0, p1);
        }

        // ---- layer 2: C2[f][e], acc init = b2 (same-wave Hs read) ----
        f32x4 acc2[8];
        #pragma unroll
        for (int mt = 0; mt < 8; ++mt)
            acc2[mt] = *(const f32x4*)&b2s[mt * 16 + lg * 4];
        #pragma unroll
        for (int kk = 0; kk < 4; ++kk) {
            bf16x8 hf = *(const bf16x8*)(HsW + lrow * 256 +
                                         ((kk * 64 + lg * 16) ^ ((lrow & 7) << 4)));
            #pragma unroll
            for (int mt = 0; mt < 8; ++mt) {
                int f = mt * 16 + lrow;
                bf16x8 wf = *(const bf16x8*)((const char*)W2s + f * 256 +
                                             ((kk * 64 + lg * 16) ^ ((f & 7) << 4)));
                acc2[mt] = __builtin_amdgcn_mfma_f32_16x16x32_bf16(wf, hf, acc2[mt], 0, 0, 0);
            }
        }

        // ---- z = wo . silu(acc2): per-lane partial over f subset, reduce lg ----
        float zp = 0.f;
        #pragma unroll
        for (int mt = 0; mt < 8; ++mt) {
            f32x4 w4 = *(const f32x4*)&wos[mt * 16 + lg * 4];
            zp += w4[0] * fsilu(acc2[mt][0]) + w4[1] * fsilu(acc2[mt][1])
                + w4[2] * fsilu(acc2[mt][2]) + w4[3] * fsilu(acc2[mt][3]);
        }
        zp += __shfl_xor(zp, 16);
        zp += __shfl_xor(zp, 32);

        // ---- scatter: 16 lanes, atomicMax packed ----
        if (lane < 16) {
            float z = zp + bo;
            int qz = (int)((z + 40.0f) * 256.0f + 0.5f);
            qz = qz < 0 ? 0 : (qz > 16383 ? 16383 : qz);
            u32 packed = 0xE0000000u | ((u32)(ei0 + lane + 1) << 14) | (u32)qz;
            atomicMax(&out[(size_t)b * NN + (size_t)i0 * N + (size_t)j0], packed);
        }
    }
}

extern "C" void kernel_launch(void* const* d_in, const int* in_sizes, int n_in,
                              void* d_out, int out_size, void* d_ws, size_t ws_size,
                              hipStream_t stream) {
    const float* edge_attr  = (const float*)d_in[0];
    const int*   edge_index = (const int*)d_in[1];
    const float* W1   = (const float*)d_in[2];
    const float* b1   = (const float*)d_in[3];
    const float* W2   = (const float*)d_in[4];
    const float* b2   = (const float*)d_in[5];
    const float* Wout = (const float*)d_in[6];
    const float* bout = (const float*)d_in[7];

    long rows = (long)in_sizes[0] / DD;        // B*E = 1,024,000
    int  E    = in_sizes[1] / 64;              // 32000 (B=32)
    int  nWT  = (int)(rows / 16);              // 64000 wave-tiles
    int  Bb   = (int)(rows / E);               // 32
    int  N    = (int)(sqrtf((float)(out_size / Bb)) + 0.5f);   // 1000

    u32* outp = (u32*)d_out;
    long n4 = (long)out_size >> 2;

    float fv = logf(1e-10f);
    u32 FB; memcpy(&FB, &fv, 4);               // all outputs < 0xE0000000 as u32

    const int SMEM = 132608;
    hipFuncSetAttribute((const void*)mlp_scatter,
                        hipFuncAttributeMaxDynamicSharedMemorySize, SMEM);

    fill_const<<<2048, 256, 0, stream>>>(outp, n4, FB);
    mlp_scatter<<<256, 1024, SMEM, stream>>>(edge_attr, edge_index, W1, b1, W2, b2,
                                             Wout, bout, outp, E, nWT, N);
    decode_sparse<<<2048, 256, 0, stream>>>(outp, n4);
}